// Round 1
// baseline (209.130 us; speedup 1.0000x reference)
//
#include <hip/hip_runtime.h>
#include <stdint.h>
#include <math.h>

static constexpr int NN  = 1024;   // N
static constexpr int DIN = 512;    // D_IN
static constexpr int DD  = 128;    // D_OUT
static constexpr int NBLK = 512;   // persistent grid size (2 blocks/CU on 256 CUs)

// ---- grid barrier state: __device__ globals are zero-initialized at load.
// Protocol: cnt self-resets to 0 after each use; gen increases monotonically
// (spin compares against captured value, so any start value works) -> safe
// across graph replays without any host-side init.
__device__ unsigned g_cnt[4];
__device__ unsigned g_gen[4];

__device__ __forceinline__ void grid_barrier(int i) {
  __syncthreads();
  if (threadIdx.x == 0) {
    __threadfence();   // release: writeback this XCD's dirty L2 before arrival
    unsigned g = __hip_atomic_load(&g_gen[i], __ATOMIC_RELAXED, __HIP_MEMORY_SCOPE_AGENT);
    unsigned a = __hip_atomic_fetch_add(&g_cnt[i], 1u, __ATOMIC_ACQ_REL, __HIP_MEMORY_SCOPE_AGENT);
    if (a == (unsigned)(NBLK - 1)) {
      __hip_atomic_store(&g_cnt[i], 0u, __ATOMIC_RELAXED, __HIP_MEMORY_SCOPE_AGENT);
      __hip_atomic_fetch_add(&g_gen[i], 1u, __ATOMIC_RELEASE, __HIP_MEMORY_SCOPE_AGENT);
    } else {
      while (__hip_atomic_load(&g_gen[i], __ATOMIC_RELAXED, __HIP_MEMORY_SCOPE_AGENT) == g) {
        __builtin_amdgcn_s_sleep(2);
      }
    }
    __threadfence();   // acquire: invalidate stale L1/L2 lines before reads
  }
  __syncthreads();
}

// ---- threefry2x32, key = jax.random.key(42) => (0,42) -------------------
__device__ __forceinline__ uint32_t rotl32(uint32_t x, uint32_t r) {
  return (x << r) | (x >> (32u - r));
}

__device__ __forceinline__ bool keep_mask(uint32_t idx) {
  uint32_t x0 = 0u, x1 = idx;
  const uint32_t k0 = 0u, k1 = 42u;
  const uint32_t k2 = k0 ^ k1 ^ 0x1BD11BDAu;
  x0 += k0; x1 += k1;
#define TF_ROUND(r) { x0 += x1; x1 = rotl32(x1, r); x1 ^= x0; }
  TF_ROUND(13u) TF_ROUND(15u) TF_ROUND(26u) TF_ROUND(6u)
  x0 += k1; x1 += k2 + 1u;
  TF_ROUND(17u) TF_ROUND(29u) TF_ROUND(16u) TF_ROUND(24u)
  x0 += k2; x1 += k0 + 2u;
  TF_ROUND(13u) TF_ROUND(15u) TF_ROUND(26u) TF_ROUND(6u)
  x0 += k0; x1 += k1 + 3u;
  TF_ROUND(17u) TF_ROUND(29u) TF_ROUND(16u) TF_ROUND(24u)
  x0 += k1; x1 += k2 + 4u;
  TF_ROUND(13u) TF_ROUND(15u) TF_ROUND(26u) TF_ROUND(6u)
  x0 += k2; x1 += k0 + 5u;
#undef TF_ROUND
  const uint32_t bits = x0 ^ x1;
  const float u = __uint_as_float((bits >> 9) | 0x3f800000u) - 1.0f;
  return u < 0.6f;
}

// ==== single persistent kernel: wtrans -> lin -> mid -> attn ==============
// LDS union: lin Xs 8*516 (16.5 KB) | mid qs/ks 2*64*68 (34.8 KB) |
// attn carve (25.4 KB). Max 34816 B -> 2 blocks/CU guaranteed (<=80 KB),
// VGPR capped at 256 by __launch_bounds__(256,2) -> all 512 blocks resident.
__global__ __launch_bounds__(256, 2) void fused_all(
    const float* __restrict__ x1, const float* __restrict__ x2,
    const float* __restrict__ x3, const float* __restrict__ x4,
    const float* __restrict__ W,  const float* __restrict__ bias,
    float* __restrict__ q, float* __restrict__ kk, float* __restrict__ v,
    float* __restrict__ sc, float* __restrict__ inv, float* __restrict__ qkm,
    float* __restrict__ WTp, float* __restrict__ out) {
  __shared__ __align__(16) float smem[8704];   // 34816 B
  const int t = threadIdx.x;
  const int bid = blockIdx.x;

  // ---- P0: WTp[k4][d][kk] = W[d][k4*4+kk] (256 KB, 16384 float4 jobs) ----
  {
    const int gid = bid * 256 + t;
    if (gid < 16384) {
      const int d = gid >> 7, k4 = gid & 127;
      *(float4*)&WTp[(size_t)k4 * (DD * 4) + d * 4] =
          *(const float4*)&W[(size_t)d * DIN + k4 * 4];
    }
  }
  grid_barrier(0);

  // ---- P1: q,k,v,scale = x_i @ W.T + b (identical to verified lin) -------
  {
    float* Xs = smem;                 // [8][516]
    const int n0 = (bid & 127) * 8;
    const int mat = bid >> 7;
    const float* x = (mat == 0) ? x1 : (mat == 1) ? x2 : (mat == 2) ? x3 : x4;
    float* o = (mat == 0) ? q : (mat == 1) ? kk : (mat == 2) ? v : sc;
#pragma unroll
    for (int it = 0; it < 4; ++it) {
      const int i = t + 256 * it;
      const int r = i >> 7, c = (i & 127) * 4;
      *(float4*)&Xs[r * 516 + c] = *(const float4*)&x[(size_t)(n0 + r) * DIN + c];
    }
    __syncthreads();
    const int d = t & 127;
    const int g2 = t >> 7;
    float acc[4] = {0.f, 0.f, 0.f, 0.f};
    const float* wp = &WTp[d * 4];
#pragma unroll 4
    for (int k4 = 0; k4 < 128; ++k4) {
      const float4 w4 = *(const float4*)&wp[(size_t)k4 * (DD * 4)];
#pragma unroll
      for (int j = 0; j < 4; ++j) {
        const float4 xa = *(const float4*)&Xs[(g2 * 4 + j) * 516 + k4 * 4];
        acc[j] = fmaf(xa.x, w4.x, fmaf(xa.y, w4.y,
                 fmaf(xa.z, w4.z, fmaf(xa.w, w4.w, acc[j]))));
      }
    }
    const float bd = bias[d];
#pragma unroll
    for (int j = 0; j < 4; ++j)
      o[(size_t)(n0 + g2 * 4 + j) * DD + d] = acc[j] + bd;
  }
  grid_barrier(1);

  // ---- P2: qk = q@k.T (blocks 0..255, K-split staging) + colsoftmax ------
  if (bid < 256) {
    float* qs = smem;                 // [64][68]
    float* ks = smem + 4352;          // [64][68]
    const int tx = t & 15, ty = t >> 4;
    const int tm = (bid & 15) * 64, tn = (bid >> 4) * 64;
    float acc[4][4] = {};
    for (int kp = 0; kp < 2; ++kp) {
      __syncthreads();
#pragma unroll
      for (int it = 0; it < 4; ++it) {
        const int i = t + 256 * it;
        const int rr = i >> 4, cc = (i & 15) * 4;
        *(float4*)&qs[rr * 68 + cc] =
            *(const float4*)&q[(size_t)(tn + rr) * DD + kp * 64 + cc];
        *(float4*)&ks[rr * 68 + cc] =
            *(const float4*)&kk[(size_t)(tm + rr) * DD + kp * 64 + cc];
      }
      __syncthreads();
      for (int k0 = 0; k0 < 64; k0 += 4) {
        float4 qv[4], kv[4];
#pragma unroll
        for (int i2 = 0; i2 < 4; ++i2) qv[i2] = *(const float4*)&qs[(ty * 4 + i2) * 68 + k0];
#pragma unroll
        for (int j = 0; j < 4; ++j) kv[j] = *(const float4*)&ks[(tx + 16 * j) * 68 + k0];
#pragma unroll
        for (int i2 = 0; i2 < 4; ++i2)
#pragma unroll
          for (int j = 0; j < 4; ++j)
            acc[i2][j] = fmaf(qv[i2].x, kv[j].x,
                         fmaf(qv[i2].y, kv[j].y,
                         fmaf(qv[i2].z, kv[j].z,
                         fmaf(qv[i2].w, kv[j].w, acc[i2][j]))));
      }
    }
#pragma unroll
    for (int i2 = 0; i2 < 4; ++i2)
#pragma unroll
      for (int j = 0; j < 4; ++j)
        qkm[(size_t)(tn + ty * 4 + i2) * NN + tm + tx + 16 * j] = acc[i2][j];
  } else if (bid < 384) {
    float* red2 = smem;               // [256]
    const int d = bid - 256;
    float vals[4];
    float mx = -INFINITY;
#pragma unroll
    for (int i = 0; i < 4; ++i) {
      vals[i] = sc[(size_t)(t + 256 * i) * DD + d];
      mx = fmaxf(mx, vals[i]);
    }
    red2[t] = mx; __syncthreads();
    for (int s = 128; s > 0; s >>= 1) {
      if (t < s) red2[t] = fmaxf(red2[t], red2[t + s]);
      __syncthreads();
    }
    mx = red2[0]; __syncthreads();
    float e[4]; float sm = 0.f;
#pragma unroll
    for (int i = 0; i < 4; ++i) { e[i] = expf(vals[i] - mx); sm += e[i]; }
    red2[t] = sm; __syncthreads();
    for (int s = 128; s > 0; s >>= 1) {
      if (t < s) red2[t] += red2[t + s];
      __syncthreads();
    }
    sm = red2[0];
#pragma unroll
    for (int i = 0; i < 4; ++i)
      inv[(size_t)(t + 256 * i) * DD + d] = e[i] / sm;
  }
  grid_barrier(2);

  // ---- P3: sparse softmax-dropout-PV, 2 rows per block -------------------
  {
    float* qkrow = smem;                       // 1024
    int*   surv  = (int*)(smem + 1024);        // 1024
    float* Pl    = smem + 2048;                // [16][130]
    float* Vs    = smem + 4128;                // [16][132]
    float* sdv   = smem + 6240;                // 128
    float* rsl   = smem + 6368;                // 128
    float* red   = smem + 6496;                // 8
    int*   cnt   = (int*)(smem + 6504);

    for (int rrow = 0; rrow < 2; ++rrow) {
      const int n = bid * 2 + rrow;
      __syncthreads();                         // guard LDS reuse across rows
      const float4 q4 = *(const float4*)&qkm[(size_t)n * NN + t * 4];
      *(float4*)&qkrow[t * 4] = q4;
      float mx = fmaxf(fmaxf(q4.x, q4.y), fmaxf(q4.z, q4.w));
#pragma unroll
      for (int o2 = 32; o2 > 0; o2 >>= 1) mx = fmaxf(mx, __shfl_xor(mx, o2));
      if ((t & 63) == 0) red[t >> 6] = mx;
      float iv = 0.f;
      if (t < DD) { iv = inv[n * DD + t]; sdv[t] = 1.0f / iv; }
      float miv = iv;
#pragma unroll
      for (int o2 = 32; o2 > 0; o2 >>= 1) miv = fmaxf(miv, __shfl_xor(miv, o2));
      if ((t & 63) == 0) red[4 + (t >> 6)] = miv;
      if (t == 0) *cnt = 0;
      __syncthreads();
      const float qkmax = fmaxf(fmaxf(red[0], red[1]), fmaxf(red[2], red[3]));
      const float maxinv = fmaxf(red[4], red[5]);
      const float th = qkmax - 30.f * maxinv;
      {
        const float qv2[4] = {q4.x, q4.y, q4.z, q4.w};
#pragma unroll
        for (int j = 0; j < 4; ++j)
          if (qv2[j] > th) { const int p = atomicAdd(cnt, 1); surv[p] = t * 4 + j; }
      }
      __syncthreads();
      const int K = *cnt;

      const int k4 = (t & 31) * 4;
      const int dbase = t >> 5;                // 0..7
      float4 acc4[16];
#pragma unroll
      for (int g = 0; g < 16; ++g) acc4[g] = make_float4(0.f, 0.f, 0.f, 0.f);
      float Sloc = 0.f;                        // valid for t < 128 (d = t)

      for (int c0 = 0; c0 < K; c0 += 16) {
        const int C = min(16, K - c0);
        __syncthreads();
        if (t < DD) {
          const float sd = sdv[t];
          const uint32_t dg = ((uint32_t)(n * DD + t)) << 10;
          for (int s = 0; s < C; ++s) {
            const int m = surv[c0 + s];
            const float arg = (qkrow[m] - qkmax) * sd;
            const float e = __expf(arg);
            Sloc += e;
            float p = 0.f;
            if (arg > -30.f) {
              if (keep_mask(dg + (uint32_t)m)) p = e;
            }
            Pl[s * 130 + t] = p;
          }
        } else {
          const int u = t - 128;
          for (int slot = u; slot < C * 32; slot += 128) {
            const int s = slot >> 5, c = (slot & 31) * 4;
            *(float4*)&Vs[s * 132 + c] =
                *(const float4*)&v[(size_t)surv[c0 + s] * DD + c];
          }
        }
        __syncthreads();
        for (int s = 0; s < C; ++s) {
          const float4 vv = *(const float4*)&Vs[s * 132 + k4];
#pragma unroll
          for (int g = 0; g < 16; ++g) {
            const float p = Pl[s * 130 + g * 8 + dbase];
            acc4[g].x = fmaf(p, vv.x, acc4[g].x);
            acc4[g].y = fmaf(p, vv.y, acc4[g].y);
            acc4[g].z = fmaf(p, vv.z, acc4[g].z);
            acc4[g].w = fmaf(p, vv.w, acc4[g].w);
          }
        }
      }

      __syncthreads();
      if (t < DD) rsl[t] = 1.0f / (Sloc * 0.6f);
      __syncthreads();
      float* op = &out[(size_t)n * (DD * DD) + t * 4];
#pragma unroll
      for (int g = 0; g < 16; ++g) {
        const float rs = rsl[g * 8 + dbase];
        float4 r2 = acc4[g];
        r2.x *= rs; r2.y *= rs; r2.z *= rs; r2.w *= rs;
        *(float4*)&op[g * 1024] = r2;
      }
    }
  }
}

// ---- launch --------------------------------------------------------------
extern "C" void kernel_launch(void* const* d_in, const int* in_sizes, int n_in,
                              void* d_out, int out_size, void* d_ws, size_t ws_size,
                              hipStream_t stream) {
  const float* x1 = (const float*)d_in[0];
  const float* x2 = (const float*)d_in[1];
  const float* x3 = (const float*)d_in[2];
  const float* x4 = (const float*)d_in[3];
  const float* W  = (const float*)d_in[4];
  const float* b  = (const float*)d_in[5];
  float* out = (float*)d_out;

  float* ws   = (float*)d_ws;
  float* q    = ws;                 // 1024*128
  float* k    = ws + 131072;
  float* v    = ws + 262144;
  float* sc   = ws + 393216;
  float* inv  = ws + 524288;
  float* qkm  = ws + 655360;        // 1024*1024
  float* WTp  = ws + 1703936;       // 512*128 transposed W

  fused_all<<<dim3(NBLK), dim3(256), 0, stream>>>(
      x1, x2, x3, x4, W, b, q, k, v, sc, inv, qkm, WTp, out);
}

// Round 2
// 155.397 us; speedup vs baseline: 1.3458x; 1.3458x over previous
//
#include <hip/hip_runtime.h>
#include <stdint.h>
#include <math.h>

static constexpr int NN  = 1024;   // N
static constexpr int DIN = 512;    // D_IN
static constexpr int DD  = 128;    // D_OUT

// ---- threefry2x32, key = jax.random.key(42) => (0,42), partitionable ----
__device__ __forceinline__ uint32_t rotl32(uint32_t x, uint32_t r) {
  return (x << r) | (x >> (32u - r));
}

__device__ __forceinline__ bool keep_mask(uint32_t idx) {
  uint32_t x0 = 0u, x1 = idx;
  const uint32_t k0 = 0u, k1 = 42u;
  const uint32_t k2 = k0 ^ k1 ^ 0x1BD11BDAu;
  x0 += k0; x1 += k1;
#define TF_ROUND(r) { x0 += x1; x1 = rotl32(x1, r); x1 ^= x0; }
  TF_ROUND(13u) TF_ROUND(15u) TF_ROUND(26u) TF_ROUND(6u)
  x0 += k1; x1 += k2 + 1u;
  TF_ROUND(17u) TF_ROUND(29u) TF_ROUND(16u) TF_ROUND(24u)
  x0 += k2; x1 += k0 + 2u;
  TF_ROUND(13u) TF_ROUND(15u) TF_ROUND(26u) TF_ROUND(6u)
  x0 += k0; x1 += k1 + 3u;
  TF_ROUND(17u) TF_ROUND(29u) TF_ROUND(16u) TF_ROUND(24u)
  x0 += k1; x1 += k2 + 4u;
  TF_ROUND(13u) TF_ROUND(15u) TF_ROUND(26u) TF_ROUND(6u)
  x0 += k2; x1 += k0 + 5u;
#undef TF_ROUND
  const uint32_t bits = x0 ^ x1;
  const float u = __uint_as_float((bits >> 9) | 0x3f800000u) - 1.0f;
  return u < 0.6f;
}

// ---- K0: WTp[k4][d][kk] = W[d][k4*4+kk]  (grid 64, block 256) ------------
__global__ __launch_bounds__(256) void wtrans_kernel(
    const float* __restrict__ W, float* __restrict__ WTp) {
  const int t = threadIdx.x;
  const int d = blockIdx.x * 2 + (t >> 7);
  const int k4 = t & 127;
  const float4 w = *(const float4*)&W[d * DIN + k4 * 4];
  *(float4*)&WTp[(size_t)k4 * (DD * 4) + d * 4] = w;
}

// ---- K1: q,k,v,scale = x_i @ W.T + b  (grid (64,4), block 256) -----------
// R2 change: 256 blocks x 16 rows (was 512 x 8). Halves WTp L2 traffic per
// CU (1 block/CU x 256 KB instead of 2) and doubles FMA per W-load (32:1).
// X reads stay wave-uniform LDS broadcasts (free). acc[8] gives 8-deep ILP
// to cover L2 latency at 1 block/CU. Accumulation order per output is
// bit-identical to the verified kernel.
__global__ __launch_bounds__(256) void lin_kernel(
    const float* __restrict__ x1, const float* __restrict__ x2,
    const float* __restrict__ x3, const float* __restrict__ x4,
    const float* __restrict__ WTp, const float* __restrict__ bias,
    float* __restrict__ q, float* __restrict__ kk,
    float* __restrict__ v, float* __restrict__ sc) {
  __shared__ float Xs[16 * 516];   // 33 KB, stride 516 (bank-safe writes)
  const int t = threadIdx.x;
  const int n0 = blockIdx.x * 16;
  const int mat = blockIdx.y;
  const float* x = (mat == 0) ? x1 : (mat == 1) ? x2 : (mat == 2) ? x3 : x4;
  float* o = (mat == 0) ? q : (mat == 1) ? kk : (mat == 2) ? v : sc;

  // stage X: 16 rows x 512 (8 float4 per thread, coalesced)
#pragma unroll
  for (int it = 0; it < 8; ++it) {
    const int i = t + 256 * it;
    const int r = i >> 7, c = (i & 127) * 4;
    *(float4*)&Xs[r * 516 + c] = *(const float4*)&x[(size_t)(n0 + r) * DIN + c];
  }
  __syncthreads();

  const int d = t & 127;           // lane-contiguous d within each wave
  const int g2 = t >> 7;           // 0/1: which 8 n-rows (wave-uniform)
  float acc[8] = {0.f, 0.f, 0.f, 0.f, 0.f, 0.f, 0.f, 0.f};
  const float* wp = &WTp[d * 4];

#pragma unroll 4
  for (int k4 = 0; k4 < 128; ++k4) {
    const float4 w4 = *(const float4*)&wp[(size_t)k4 * (DD * 4)];
#pragma unroll
    for (int j = 0; j < 8; ++j) {
      const float4 xa = *(const float4*)&Xs[(g2 * 8 + j) * 516 + k4 * 4];
      acc[j] = fmaf(xa.x, w4.x, fmaf(xa.y, w4.y,
               fmaf(xa.z, w4.z, fmaf(xa.w, w4.w, acc[j]))));
    }
  }

  const float bd = bias[d];
#pragma unroll
  for (int j = 0; j < 8; ++j)
    o[(size_t)(n0 + g2 * 8 + j) * DD + d] = acc[j] + bd;
}

// ---- K2: fused qk = q@k.T (blocks 0..255) + colsoftmax (blocks 256..383) -
__global__ __launch_bounds__(256) void mid_kernel(
    const float* __restrict__ q, const float* __restrict__ kref,
    const float* __restrict__ sc, float* __restrict__ qkout,
    float* __restrict__ inv) {
  const int t = threadIdx.x;
  if (blockIdx.x < 256) {
    // ---- qk: 64x64 tile, 4x4 per thread ----
    __shared__ float qs[64 * 132];
    __shared__ float ks[64 * 132];
    const int tx = t & 15, ty = t >> 4;
    const int tm = (blockIdx.x & 15) * 64, tn = (blockIdx.x >> 4) * 64;
    for (int it = 0; it < 8; ++it) {
      const int i = t + 256 * it;
      const int r = i >> 5, c = (i & 31) * 4;
      *(float4*)&qs[r * 132 + c] = *(const float4*)&q[(tn + r) * DD + c];
      *(float4*)&ks[r * 132 + c] = *(const float4*)&kref[(tm + r) * DD + c];
    }
    __syncthreads();
    float acc[4][4] = {};
    for (int k0 = 0; k0 < DD; k0 += 4) {
      float4 qv[4], kv[4];
#pragma unroll
      for (int i = 0; i < 4; ++i) qv[i] = *(const float4*)&qs[(ty * 4 + i) * 132 + k0];
#pragma unroll
      for (int j = 0; j < 4; ++j) kv[j] = *(const float4*)&ks[(tx + 16 * j) * 132 + k0];
#pragma unroll
      for (int i = 0; i < 4; ++i)
#pragma unroll
        for (int j = 0; j < 4; ++j)
          acc[i][j] = fmaf(qv[i].x, kv[j].x,
                      fmaf(qv[i].y, kv[j].y,
                      fmaf(qv[i].z, kv[j].z,
                      fmaf(qv[i].w, kv[j].w, acc[i][j]))));
    }
#pragma unroll
    for (int i = 0; i < 4; ++i)
#pragma unroll
      for (int j = 0; j < 4; ++j)
        qkout[(size_t)(tn + ty * 4 + i) * NN + tm + tx + 16 * j] = acc[i][j];
  } else {
    // ---- column softmax over n for d = blockIdx.x - 256 ----
    __shared__ float red[256];
    const int d = blockIdx.x - 256;
    float vals[4];
    float mx = -INFINITY;
#pragma unroll
    for (int i = 0; i < 4; ++i) {
      vals[i] = sc[(size_t)(t + 256 * i) * DD + d];
      mx = fmaxf(mx, vals[i]);
    }
    red[t] = mx; __syncthreads();
    for (int s = 128; s > 0; s >>= 1) {
      if (t < s) red[t] = fmaxf(red[t], red[t + s]);
      __syncthreads();
    }
    mx = red[0]; __syncthreads();
    float e[4]; float sm = 0.f;
#pragma unroll
    for (int i = 0; i < 4; ++i) { e[i] = expf(vals[i] - mx); sm += e[i]; }
    red[t] = sm; __syncthreads();
    for (int s = 128; s > 0; s >>= 1) {
      if (t < s) red[t] += red[t + s];
      __syncthreads();
    }
    sm = red[0];
#pragma unroll
    for (int i = 0; i < 4; ++i)
      inv[(size_t)(t + 256 * i) * DD + d] = e[i] / sm;
  }
}

// ---- K3: sparse softmax-dropout-PV  (grid 1024, block 256) ---------------
__global__ __launch_bounds__(256) void attn_kernel(
    const float* __restrict__ qk, const float* __restrict__ inv_scale,
    const float* __restrict__ v, float* __restrict__ out) {
  __shared__ float qkrow[NN];      // 4 KB
  __shared__ float red[8];
  __shared__ int   surv[NN];       // 4 KB (worst case dense -> still correct)
  __shared__ float Pl[16][130];    // P chunk [s][d]
  __shared__ float Vs[16][132];    // V chunk [s][k]
  __shared__ float sdv[DD];
  __shared__ float rsl[DD];
  __shared__ int   cnt;

  const int n = blockIdx.x;
  const int t = threadIdx.x;

  const float4 q4 = *(const float4*)&qk[(size_t)n * NN + t * 4];
  *(float4*)&qkrow[t * 4] = q4;
  float mx = fmaxf(fmaxf(q4.x, q4.y), fmaxf(q4.z, q4.w));
#pragma unroll
  for (int o = 32; o > 0; o >>= 1) mx = fmaxf(mx, __shfl_xor(mx, o));
  if ((t & 63) == 0) red[t >> 6] = mx;
  float iv = 0.f;
  if (t < DD) { iv = inv_scale[n * DD + t]; sdv[t] = 1.0f / iv; }
  float miv = iv;
#pragma unroll
  for (int o = 32; o > 0; o >>= 1) miv = fmaxf(miv, __shfl_xor(miv, o));
  if ((t & 63) == 0) red[4 + (t >> 6)] = miv;
  if (t == 0) cnt = 0;
  __syncthreads();
  const float qkmax = fmaxf(fmaxf(red[0], red[1]), fmaxf(red[2], red[3]));
  const float maxinv = fmaxf(red[4], red[5]);
  const float th = qkmax - 30.f * maxinv;

  {
    const float qv[4] = {q4.x, q4.y, q4.z, q4.w};
#pragma unroll
    for (int j = 0; j < 4; ++j)
      if (qv[j] > th) { const int p = atomicAdd(&cnt, 1); surv[p] = t * 4 + j; }
  }
  __syncthreads();
  const int K = cnt;

  const int k4 = (t & 31) * 4;
  const int dbase = t >> 5;       // 0..7
  float4 acc4[16];
#pragma unroll
  for (int g = 0; g < 16; ++g) acc4[g] = make_float4(0.f, 0.f, 0.f, 0.f);
  float Sloc = 0.f;               // valid for t < 128 (d = t)

  for (int c0 = 0; c0 < K; c0 += 16) {
    const int C = min(16, K - c0);
    __syncthreads();
    if (t < DD) {
      const float sd = sdv[t];
      const uint32_t dg = ((uint32_t)(n * DD + t)) << 10;
      for (int s = 0; s < C; ++s) {
        const int m = surv[c0 + s];
        const float arg = (qkrow[m] - qkmax) * sd;
        const float e = __expf(arg);
        Sloc += e;
        float p = 0.f;
        if (arg > -30.f) {
          if (keep_mask(dg + (uint32_t)m)) p = e;
        }
        Pl[s][t] = p;
      }
    } else {
      const int u = t - 128;
      for (int slot = u; slot < C * 32; slot += 128) {
        const int s = slot >> 5, c = (slot & 31) * 4;
        *(float4*)&Vs[s][c] = *(const float4*)&v[(size_t)surv[c0 + s] * DD + c];
      }
    }
    __syncthreads();
    for (int s = 0; s < C; ++s) {
      const float4 vv = *(const float4*)&Vs[s][k4];
#pragma unroll
      for (int g = 0; g < 16; ++g) {
        const float p = Pl[s][g * 8 + dbase];
        acc4[g].x = fmaf(p, vv.x, acc4[g].x);
        acc4[g].y = fmaf(p, vv.y, acc4[g].y);
        acc4[g].z = fmaf(p, vv.z, acc4[g].z);
        acc4[g].w = fmaf(p, vv.w, acc4[g].w);
      }
    }
  }

  __syncthreads();
  if (t < DD) rsl[t] = 1.0f / (Sloc * 0.6f);
  __syncthreads();
  float* op = &out[(size_t)n * (DD * DD) + t * 4];
#pragma unroll
  for (int g = 0; g < 16; ++g) {
    const float rs = rsl[g * 8 + dbase];
    float4 r = acc4[g];
    r.x *= rs; r.y *= rs; r.z *= rs; r.w *= rs;
    *(float4*)&op[g * 1024] = r;
  }
}

// ---- launch --------------------------------------------------------------
extern "C" void kernel_launch(void* const* d_in, const int* in_sizes, int n_in,
                              void* d_out, int out_size, void* d_ws, size_t ws_size,
                              hipStream_t stream) {
  const float* x1 = (const float*)d_in[0];
  const float* x2 = (const float*)d_in[1];
  const float* x3 = (const float*)d_in[2];
  const float* x4 = (const float*)d_in[3];
  const float* W  = (const float*)d_in[4];
  const float* b  = (const float*)d_in[5];
  float* out = (float*)d_out;

  float* ws   = (float*)d_ws;
  float* q    = ws;                 // 1024*128
  float* k    = ws + 131072;
  float* v    = ws + 262144;
  float* sc   = ws + 393216;
  float* inv  = ws + 524288;
  float* qkm  = ws + 655360;        // 1024*1024
  float* WTp  = ws + 1703936;       // 512*128 transposed W

  wtrans_kernel<<<dim3(64), 256, 0, stream>>>(W, WTp);
  lin_kernel<<<dim3(64, 4), 256, 0, stream>>>(x1, x2, x3, x4, WTp, b, q, k, v, sc);
  mid_kernel<<<dim3(384), 256, 0, stream>>>(q, k, sc, qkm, inv);
  attn_kernel<<<NN, 256, 0, stream>>>(qkm, inv, v, out);
}

// Round 3
// 135.661 us; speedup vs baseline: 1.5416x; 1.1455x over previous
//
#include <hip/hip_runtime.h>
#include <stdint.h>
#include <math.h>

static constexpr int NN  = 1024;   // N
static constexpr int DIN = 512;    // D_IN
static constexpr int DD  = 128;    // D_OUT

// ---- threefry2x32, key = jax.random.key(42) => (0,42), partitionable ----
__device__ __forceinline__ uint32_t rotl32(uint32_t x, uint32_t r) {
  return (x << r) | (x >> (32u - r));
}

__device__ __forceinline__ bool keep_mask(uint32_t idx) {
  uint32_t x0 = 0u, x1 = idx;
  const uint32_t k0 = 0u, k1 = 42u;
  const uint32_t k2 = k0 ^ k1 ^ 0x1BD11BDAu;
  x0 += k0; x1 += k1;
#define TF_ROUND(r) { x0 += x1; x1 = rotl32(x1, r); x1 ^= x0; }
  TF_ROUND(13u) TF_ROUND(15u) TF_ROUND(26u) TF_ROUND(6u)
  x0 += k1; x1 += k2 + 1u;
  TF_ROUND(17u) TF_ROUND(29u) TF_ROUND(16u) TF_ROUND(24u)
  x0 += k2; x1 += k0 + 2u;
  TF_ROUND(13u) TF_ROUND(15u) TF_ROUND(26u) TF_ROUND(6u)
  x0 += k0; x1 += k1 + 3u;
  TF_ROUND(17u) TF_ROUND(29u) TF_ROUND(16u) TF_ROUND(24u)
  x0 += k1; x1 += k2 + 4u;
  TF_ROUND(13u) TF_ROUND(15u) TF_ROUND(26u) TF_ROUND(6u)
  x0 += k2; x1 += k0 + 5u;
#undef TF_ROUND
  const uint32_t bits = x0 ^ x1;
  const float u = __uint_as_float((bits >> 9) | 0x3f800000u) - 1.0f;
  return u < 0.6f;
}

// ---- K0: WTp[k4][d][kk] = W[d][k4*4+kk]  (grid 64, block 256) ------------
__global__ __launch_bounds__(256) void wtrans_kernel(
    const float* __restrict__ W, float* __restrict__ WTp) {
  const int t = threadIdx.x;
  const int d = blockIdx.x * 2 + (t >> 7);
  const int k4 = t & 127;
  const float4 w = *(const float4*)&W[d * DIN + k4 * 4];
  *(float4*)&WTp[(size_t)k4 * (DD * 4) + d * 4] = w;
}

// ---- K1: q,k,v,scale = x_i @ W.T + b  (grid (128,4), block 256) ----------
// R3 change: NO LDS staging of X. Round-2 arithmetic showed the wave-uniform
// broadcast ds_read_b128 path is LDS-pipe-bound: 8 waves/CU x 128 iter x
// 4 reads x 12cyc ~= 20us. X rows are wave-uniform (g2 = t>>7), so read X
// straight from global with a readfirstlane-forced uniform base: compiler
// scalarizes to s_load (SMEM pipe) or emits one 16B wave-uniform L1-hit
// vector load. LDS pipe usage -> 0. FMA chain order identical to verified
// kernel -> bit-identical output.
__global__ __launch_bounds__(256) void lin_kernel(
    const float* __restrict__ x1, const float* __restrict__ x2,
    const float* __restrict__ x3, const float* __restrict__ x4,
    const float* __restrict__ WTp, const float* __restrict__ bias,
    float* __restrict__ q, float* __restrict__ kk,
    float* __restrict__ v, float* __restrict__ sc) {
  const int t = threadIdx.x;
  const int n0 = blockIdx.x * 8;
  const int mat = blockIdx.y;
  const float* x = (mat == 0) ? x1 : (mat == 1) ? x2 : (mat == 2) ? x3 : x4;
  float* o = (mat == 0) ? q : (mat == 1) ? kk : (mat == 2) ? v : sc;

  const int d = t & 127;                     // lane-contiguous d per wave
  const int g2 = __builtin_amdgcn_readfirstlane(t >> 7);  // wave-uniform 0/1
  float acc[4] = {0.f, 0.f, 0.f, 0.f};
  const float* wp = &WTp[d * 4];
  // 4 wave-uniform X row bases (rows n0+g2*4 .. n0+g2*4+3)
  const float* xr0 = x + (size_t)(n0 + g2 * 4 + 0) * DIN;
  const float* xr1 = x + (size_t)(n0 + g2 * 4 + 1) * DIN;
  const float* xr2 = x + (size_t)(n0 + g2 * 4 + 2) * DIN;
  const float* xr3 = x + (size_t)(n0 + g2 * 4 + 3) * DIN;

#pragma unroll 4
  for (int k4 = 0; k4 < 128; ++k4) {
    const float4 w4 = *(const float4*)&wp[(size_t)k4 * (DD * 4)];
    const float4 xa0 = *(const float4*)&xr0[k4 * 4];
    const float4 xa1 = *(const float4*)&xr1[k4 * 4];
    const float4 xa2 = *(const float4*)&xr2[k4 * 4];
    const float4 xa3 = *(const float4*)&xr3[k4 * 4];
    acc[0] = fmaf(xa0.x, w4.x, fmaf(xa0.y, w4.y,
             fmaf(xa0.z, w4.z, fmaf(xa0.w, w4.w, acc[0]))));
    acc[1] = fmaf(xa1.x, w4.x, fmaf(xa1.y, w4.y,
             fmaf(xa1.z, w4.z, fmaf(xa1.w, w4.w, acc[1]))));
    acc[2] = fmaf(xa2.x, w4.x, fmaf(xa2.y, w4.y,
             fmaf(xa2.z, w4.z, fmaf(xa2.w, w4.w, acc[2]))));
    acc[3] = fmaf(xa3.x, w4.x, fmaf(xa3.y, w4.y,
             fmaf(xa3.z, w4.z, fmaf(xa3.w, w4.w, acc[3]))));
  }

  const float bd = bias[d];
#pragma unroll
  for (int j = 0; j < 4; ++j)
    o[(size_t)(n0 + g2 * 4 + j) * DD + d] = acc[j] + bd;
}

// ---- K2: fused qk = q@k.T (blocks 0..255) + colsoftmax (blocks 256..383) -
__global__ __launch_bounds__(256) void mid_kernel(
    const float* __restrict__ q, const float* __restrict__ kref,
    const float* __restrict__ sc, float* __restrict__ qkout,
    float* __restrict__ inv) {
  const int t = threadIdx.x;
  if (blockIdx.x < 256) {
    // ---- qk: 64x64 tile, 4x4 per thread ----
    __shared__ float qs[64 * 132];
    __shared__ float ks[64 * 132];
    const int tx = t & 15, ty = t >> 4;
    const int tm = (blockIdx.x & 15) * 64, tn = (blockIdx.x >> 4) * 64;
    for (int it = 0; it < 8; ++it) {
      const int i = t + 256 * it;
      const int r = i >> 5, c = (i & 31) * 4;
      *(float4*)&qs[r * 132 + c] = *(const float4*)&q[(tn + r) * DD + c];
      *(float4*)&ks[r * 132 + c] = *(const float4*)&kref[(tm + r) * DD + c];
    }
    __syncthreads();
    float acc[4][4] = {};
    for (int k0 = 0; k0 < DD; k0 += 4) {
      float4 qv[4], kv[4];
#pragma unroll
      for (int i = 0; i < 4; ++i) qv[i] = *(const float4*)&qs[(ty * 4 + i) * 132 + k0];
#pragma unroll
      for (int j = 0; j < 4; ++j) kv[j] = *(const float4*)&ks[(tx + 16 * j) * 132 + k0];
#pragma unroll
      for (int i = 0; i < 4; ++i)
#pragma unroll
        for (int j = 0; j < 4; ++j)
          acc[i][j] = fmaf(qv[i].x, kv[j].x,
                      fmaf(qv[i].y, kv[j].y,
                      fmaf(qv[i].z, kv[j].z,
                      fmaf(qv[i].w, kv[j].w, acc[i][j]))));
    }
#pragma unroll
    for (int i = 0; i < 4; ++i)
#pragma unroll
      for (int j = 0; j < 4; ++j)
        qkout[(size_t)(tn + ty * 4 + i) * NN + tm + tx + 16 * j] = acc[i][j];
  } else {
    // ---- column softmax over n for d = blockIdx.x - 256 ----
    __shared__ float red[256];
    const int d = blockIdx.x - 256;
    float vals[4];
    float mx = -INFINITY;
#pragma unroll
    for (int i = 0; i < 4; ++i) {
      vals[i] = sc[(size_t)(t + 256 * i) * DD + d];
      mx = fmaxf(mx, vals[i]);
    }
    red[t] = mx; __syncthreads();
    for (int s = 128; s > 0; s >>= 1) {
      if (t < s) red[t] = fmaxf(red[t], red[t + s]);
      __syncthreads();
    }
    mx = red[0]; __syncthreads();
    float e[4]; float sm = 0.f;
#pragma unroll
    for (int i = 0; i < 4; ++i) { e[i] = expf(vals[i] - mx); sm += e[i]; }
    red[t] = sm; __syncthreads();
    for (int s = 128; s > 0; s >>= 1) {
      if (t < s) red[t] += red[t + s];
      __syncthreads();
    }
    sm = red[0];
#pragma unroll
    for (int i = 0; i < 4; ++i)
      inv[(size_t)(t + 256 * i) * DD + d] = e[i] / sm;
  }
}

// ---- K3: sparse softmax-dropout-PV  (grid 1024, block 256) ---------------
__global__ __launch_bounds__(256) void attn_kernel(
    const float* __restrict__ qk, const float* __restrict__ inv_scale,
    const float* __restrict__ v, float* __restrict__ out) {
  __shared__ float qkrow[NN];      // 4 KB
  __shared__ float red[8];
  __shared__ int   surv[NN];       // 4 KB (worst case dense -> still correct)
  __shared__ float Pl[16][130];    // P chunk [s][d]
  __shared__ float Vs[16][132];    // V chunk [s][k]
  __shared__ float sdv[DD];
  __shared__ float rsl[DD];
  __shared__ int   cnt;

  const int n = blockIdx.x;
  const int t = threadIdx.x;

  const float4 q4 = *(const float4*)&qk[(size_t)n * NN + t * 4];
  *(float4*)&qkrow[t * 4] = q4;
  float mx = fmaxf(fmaxf(q4.x, q4.y), fmaxf(q4.z, q4.w));
#pragma unroll
  for (int o = 32; o > 0; o >>= 1) mx = fmaxf(mx, __shfl_xor(mx, o));
  if ((t & 63) == 0) red[t >> 6] = mx;
  float iv = 0.f;
  if (t < DD) { iv = inv_scale[n * DD + t]; sdv[t] = 1.0f / iv; }
  float miv = iv;
#pragma unroll
  for (int o = 32; o > 0; o >>= 1) miv = fmaxf(miv, __shfl_xor(miv, o));
  if ((t & 63) == 0) red[4 + (t >> 6)] = miv;
  if (t == 0) cnt = 0;
  __syncthreads();
  const float qkmax = fmaxf(fmaxf(red[0], red[1]), fmaxf(red[2], red[3]));
  const float maxinv = fmaxf(red[4], red[5]);
  const float th = qkmax - 30.f * maxinv;

  {
    const float qv[4] = {q4.x, q4.y, q4.z, q4.w};
#pragma unroll
    for (int j = 0; j < 4; ++j)
      if (qv[j] > th) { const int p = atomicAdd(&cnt, 1); surv[p] = t * 4 + j; }
  }
  __syncthreads();
  const int K = cnt;

  const int k4 = (t & 31) * 4;
  const int dbase = t >> 5;       // 0..7
  float4 acc4[16];
#pragma unroll
  for (int g = 0; g < 16; ++g) acc4[g] = make_float4(0.f, 0.f, 0.f, 0.f);
  float Sloc = 0.f;               // valid for t < 128 (d = t)

  for (int c0 = 0; c0 < K; c0 += 16) {
    const int C = min(16, K - c0);
    __syncthreads();
    if (t < DD) {
      const float sd = sdv[t];
      const uint32_t dg = ((uint32_t)(n * DD + t)) << 10;
      for (int s = 0; s < C; ++s) {
        const int m = surv[c0 + s];
        const float arg = (qkrow[m] - qkmax) * sd;
        const float e = __expf(arg);
        Sloc += e;
        float p = 0.f;
        if (arg > -30.f) {
          if (keep_mask(dg + (uint32_t)m)) p = e;
        }
        Pl[s][t] = p;
      }
    } else {
      const int u = t - 128;
      for (int slot = u; slot < C * 32; slot += 128) {
        const int s = slot >> 5, c = (slot & 31) * 4;
        *(float4*)&Vs[s][c] = *(const float4*)&v[(size_t)surv[c0 + s] * DD + c];
      }
    }
    __syncthreads();
    for (int s = 0; s < C; ++s) {
      const float4 vv = *(const float4*)&Vs[s][k4];
#pragma unroll
      for (int g = 0; g < 16; ++g) {
        const float p = Pl[s][g * 8 + dbase];
        acc4[g].x = fmaf(p, vv.x, acc4[g].x);
        acc4[g].y = fmaf(p, vv.y, acc4[g].y);
        acc4[g].z = fmaf(p, vv.z, acc4[g].z);
        acc4[g].w = fmaf(p, vv.w, acc4[g].w);
      }
    }
  }

  __syncthreads();
  if (t < DD) rsl[t] = 1.0f / (Sloc * 0.6f);
  __syncthreads();
  float* op = &out[(size_t)n * (DD * DD) + t * 4];
#pragma unroll
  for (int g = 0; g < 16; ++g) {
    const float rs = rsl[g * 8 + dbase];
    float4 r = acc4[g];
    r.x *= rs; r.y *= rs; r.z *= rs; r.w *= rs;
    *(float4*)&op[g * 1024] = r;
  }
}

// ---- launch --------------------------------------------------------------
extern "C" void kernel_launch(void* const* d_in, const int* in_sizes, int n_in,
                              void* d_out, int out_size, void* d_ws, size_t ws_size,
                              hipStream_t stream) {
  const float* x1 = (const float*)d_in[0];
  const float* x2 = (const float*)d_in[1];
  const float* x3 = (const float*)d_in[2];
  const float* x4 = (const float*)d_in[3];
  const float* W  = (const float*)d_in[4];
  const float* b  = (const float*)d_in[5];
  float* out = (float*)d_out;

  float* ws   = (float*)d_ws;
  float* q    = ws;                 // 1024*128
  float* k    = ws + 131072;
  float* v    = ws + 262144;
  float* sc   = ws + 393216;
  float* inv  = ws + 524288;
  float* qkm  = ws + 655360;        // 1024*1024
  float* WTp  = ws + 1703936;       // 512*128 transposed W

  wtrans_kernel<<<dim3(64), 256, 0, stream>>>(W, WTp);
  lin_kernel<<<dim3(128, 4), 256, 0, stream>>>(x1, x2, x3, x4, WTp, b, q, k, v, sc);
  mid_kernel<<<dim3(384), 256, 0, stream>>>(q, k, sc, qkm, inv);
  attn_kernel<<<NN, 256, 0, stream>>>(qkm, inv, v, out);
}

// Round 7
// 120.406 us; speedup vs baseline: 1.7369x; 1.1267x over previous
//
#include <hip/hip_runtime.h>
#include <stdint.h>
#include <math.h>

static constexpr int NN  = 1024;   // N
static constexpr int DIN = 512;    // D_IN
static constexpr int DD  = 128;    // D_OUT

// ---- threefry2x32, key = jax.random.key(42) => (0,42), partitionable ----
__device__ __forceinline__ uint32_t rotl32(uint32_t x, uint32_t r) {
  return (x << r) | (x >> (32u - r));
}

__device__ __forceinline__ bool keep_mask(uint32_t idx) {
  uint32_t x0 = 0u, x1 = idx;
  const uint32_t k0 = 0u, k1 = 42u;
  const uint32_t k2 = k0 ^ k1 ^ 0x1BD11BDAu;
  x0 += k0; x1 += k1;
#define TF_ROUND(r) { x0 += x1; x1 = rotl32(x1, r); x1 ^= x0; }
  TF_ROUND(13u) TF_ROUND(15u) TF_ROUND(26u) TF_ROUND(6u)
  x0 += k1; x1 += k2 + 1u;
  TF_ROUND(17u) TF_ROUND(29u) TF_ROUND(16u) TF_ROUND(24u)
  x0 += k2; x1 += k0 + 2u;
  TF_ROUND(13u) TF_ROUND(15u) TF_ROUND(26u) TF_ROUND(6u)
  x0 += k0; x1 += k1 + 3u;
  TF_ROUND(17u) TF_ROUND(29u) TF_ROUND(16u) TF_ROUND(24u)
  x0 += k1; x1 += k2 + 4u;
  TF_ROUND(13u) TF_ROUND(15u) TF_ROUND(26u) TF_ROUND(6u)
  x0 += k2; x1 += k0 + 5u;
#undef TF_ROUND
  const uint32_t bits = x0 ^ x1;
  const float u = __uint_as_float((bits >> 9) | 0x3f800000u) - 1.0f;
  return u < 0.6f;
}

// ---- K0: WTp[k4][d][kk] = W[d][k4*4+kk]  (grid 64, block 256) ------------
__global__ __launch_bounds__(256) void wtrans_kernel(
    const float* __restrict__ W, float* __restrict__ WTp) {
  const int t = threadIdx.x;
  const int d = blockIdx.x * 2 + (t >> 7);
  const int k4 = t & 127;
  const float4 w = *(const float4*)&W[d * DIN + k4 * 4];
  *(float4*)&WTp[(size_t)k4 * (DD * 4) + d * 4] = w;
}

// ---- K1: q,k,v,scale = x_i @ W.T + b  (grid (128,4), block 256) ----------
// R7: disjoint-row waves. R0 issued 16 broadcast ds_read_b128 per k4 per
// block (4 waves x 4 rows) for only 8 rows -- waves duplicated each other's
// broadcasts because each covered half the d-range. Now wave w owns rows
// {2w, 2w+1} with ALL 128 d (2 per lane: d2, d2+64): 8 broadcasts per k4
// per block (2 per wave, zero duplication). LDS-pipe cost halves
// (~20us -> ~10us). The 4x cross-wave W re-read is L1-absorbed (lockstep
// k4 sweep; 256KB unique W per block, L2-resident). Per-output FMA chain
// order identical to R0 -> bit-identical results. Grid stays 512 blocks
// (R2 lesson: never drop to 1 block/CU).
__global__ __launch_bounds__(256) void lin_kernel(
    const float* __restrict__ x1, const float* __restrict__ x2,
    const float* __restrict__ x3, const float* __restrict__ x4,
    const float* __restrict__ WTp, const float* __restrict__ bias,
    float* __restrict__ q, float* __restrict__ kk,
    float* __restrict__ v, float* __restrict__ sc) {
  __shared__ float Xs[8 * 516];    // 16.5 KB, stride 516 (bank-safe writes)
  const int t = threadIdx.x;
  const int n0 = blockIdx.x * 8;
  const int mat = blockIdx.y;
  const float* x = (mat == 0) ? x1 : (mat == 1) ? x2 : (mat == 2) ? x3 : x4;
  float* o = (mat == 0) ? q : (mat == 1) ? kk : (mat == 2) ? v : sc;

  // stage X: 8 rows x 512 (4 float4 per thread, coalesced) -- as R0
#pragma unroll
  for (int it = 0; it < 4; ++it) {
    const int i = t + 256 * it;
    const int r = i >> 7, c = (i & 127) * 4;
    *(float4*)&Xs[r * 516 + c] = *(const float4*)&x[(size_t)(n0 + r) * DIN + c];
  }
  __syncthreads();

  const int d2 = t & 63;           // lane d base (covers d2 and d2+64)
  const int w  = t >> 6;           // wave 0..3 -> rows 2w, 2w+1
  const int r0 = w * 2;
  float accA0 = 0.f, accB0 = 0.f;  // row r0:   d2, d2+64
  float accA1 = 0.f, accB1 = 0.f;  // row r0+1: d2, d2+64
  const float* wpA = &WTp[(d2     ) * 4];
  const float* wpB = &WTp[(d2 + 64) * 4];

#pragma unroll 4
  for (int k4 = 0; k4 < 128; ++k4) {
    const float4 wA = *(const float4*)&wpA[(size_t)k4 * (DD * 4)];
    const float4 wB = *(const float4*)&wpB[(size_t)k4 * (DD * 4)];
    const float4 x0 = *(const float4*)&Xs[(r0    ) * 516 + k4 * 4];
    const float4 x1v = *(const float4*)&Xs[(r0 + 1) * 516 + k4 * 4];
    accA0 = fmaf(x0.x, wA.x, fmaf(x0.y, wA.y,
            fmaf(x0.z, wA.z, fmaf(x0.w, wA.w, accA0))));
    accB0 = fmaf(x0.x, wB.x, fmaf(x0.y, wB.y,
            fmaf(x0.z, wB.z, fmaf(x0.w, wB.w, accB0))));
    accA1 = fmaf(x1v.x, wA.x, fmaf(x1v.y, wA.y,
            fmaf(x1v.z, wA.z, fmaf(x1v.w, wA.w, accA1))));
    accB1 = fmaf(x1v.x, wB.x, fmaf(x1v.y, wB.y,
            fmaf(x1v.z, wB.z, fmaf(x1v.w, wB.w, accB1))));
  }

  const float bA = bias[d2];
  const float bB = bias[d2 + 64];
  o[(size_t)(n0 + r0    ) * DD + d2     ] = accA0 + bA;
  o[(size_t)(n0 + r0    ) * DD + d2 + 64] = accB0 + bB;
  o[(size_t)(n0 + r0 + 1) * DD + d2     ] = accA1 + bA;
  o[(size_t)(n0 + r0 + 1) * DD + d2 + 64] = accB1 + bB;
}

// ---- K2: fused qk = q@k.T (blocks 0..255) + colsoftmax (blocks 256..383) -
__global__ __launch_bounds__(256) void mid_kernel(
    const float* __restrict__ q, const float* __restrict__ kref,
    const float* __restrict__ sc, float* __restrict__ qkout,
    float* __restrict__ inv) {
  const int t = threadIdx.x;
  if (blockIdx.x < 256) {
    // ---- qk: 64x64 tile, 4x4 per thread ----
    __shared__ float qs[64 * 132];
    __shared__ float ks[64 * 132];
    const int tx = t & 15, ty = t >> 4;
    const int tm = (blockIdx.x & 15) * 64, tn = (blockIdx.x >> 4) * 64;
    for (int it = 0; it < 8; ++it) {
      const int i = t + 256 * it;
      const int r = i >> 5, c = (i & 31) * 4;
      *(float4*)&qs[r * 132 + c] = *(const float4*)&q[(tn + r) * DD + c];
      *(float4*)&ks[r * 132 + c] = *(const float4*)&kref[(tm + r) * DD + c];
    }
    __syncthreads();
    float acc[4][4] = {};
    for (int k0 = 0; k0 < DD; k0 += 4) {
      float4 qv[4], kv[4];
#pragma unroll
      for (int i = 0; i < 4; ++i) qv[i] = *(const float4*)&qs[(ty * 4 + i) * 132 + k0];
#pragma unroll
      for (int j = 0; j < 4; ++j) kv[j] = *(const float4*)&ks[(tx + 16 * j) * 132 + k0];
#pragma unroll
      for (int i = 0; i < 4; ++i)
#pragma unroll
        for (int j = 0; j < 4; ++j)
          acc[i][j] = fmaf(qv[i].x, kv[j].x,
                      fmaf(qv[i].y, kv[j].y,
                      fmaf(qv[i].z, kv[j].z,
                      fmaf(qv[i].w, kv[j].w, acc[i][j]))));
    }
#pragma unroll
    for (int i = 0; i < 4; ++i)
#pragma unroll
      for (int j = 0; j < 4; ++j)
        qkout[(size_t)(tn + ty * 4 + i) * NN + tm + tx + 16 * j] = acc[i][j];
  } else {
    // ---- column softmax over n for d = blockIdx.x - 256 ----
    __shared__ float red[256];
    const int d = blockIdx.x - 256;
    float vals[4];
    float mx = -INFINITY;
#pragma unroll
    for (int i = 0; i < 4; ++i) {
      vals[i] = sc[(size_t)(t + 256 * i) * DD + d];
      mx = fmaxf(mx, vals[i]);
    }
    red[t] = mx; __syncthreads();
    for (int s = 128; s > 0; s >>= 1) {
      if (t < s) red[t] = fmaxf(red[t], red[t + s]);
      __syncthreads();
    }
    mx = red[0]; __syncthreads();
    float e[4]; float sm = 0.f;
#pragma unroll
    for (int i = 0; i < 4; ++i) { e[i] = expf(vals[i] - mx); sm += e[i]; }
    red[t] = sm; __syncthreads();
    for (int s = 128; s > 0; s >>= 1) {
      if (t < s) red[t] += red[t + s];
      __syncthreads();
    }
    sm = red[0];
#pragma unroll
    for (int i = 0; i < 4; ++i)
      inv[(size_t)(t + 256 * i) * DD + d] = e[i] / sm;
  }
}

// ---- K3: sparse softmax-dropout-PV  (grid 1024, block 256) ---------------
__global__ __launch_bounds__(256) void attn_kernel(
    const float* __restrict__ qk, const float* __restrict__ inv_scale,
    const float* __restrict__ v, float* __restrict__ out) {
  __shared__ float qkrow[NN];      // 4 KB
  __shared__ float red[8];
  __shared__ int   surv[NN];       // 4 KB (worst case dense -> still correct)
  __shared__ float Pl[16][130];    // P chunk [s][d]
  __shared__ float Vs[16][132];    // V chunk [s][k]
  __shared__ float sdv[DD];
  __shared__ float rsl[DD];
  __shared__ int   cnt;

  const int n = blockIdx.x;
  const int t = threadIdx.x;

  const float4 q4 = *(const float4*)&qk[(size_t)n * NN + t * 4];
  *(float4*)&qkrow[t * 4] = q4;
  float mx = fmaxf(fmaxf(q4.x, q4.y), fmaxf(q4.z, q4.w));
#pragma unroll
  for (int o = 32; o > 0; o >>= 1) mx = fmaxf(mx, __shfl_xor(mx, o));
  if ((t & 63) == 0) red[t >> 6] = mx;
  float iv = 0.f;
  if (t < DD) { iv = inv_scale[n * DD + t]; sdv[t] = 1.0f / iv; }
  float miv = iv;
#pragma unroll
  for (int o = 32; o > 0; o >>= 1) miv = fmaxf(miv, __shfl_xor(miv, o));
  if ((t & 63) == 0) red[4 + (t >> 6)] = miv;
  if (t == 0) cnt = 0;
  __syncthreads();
  const float qkmax = fmaxf(fmaxf(red[0], red[1]), fmaxf(red[2], red[3]));
  const float maxinv = fmaxf(red[4], red[5]);
  const float th = qkmax - 30.f * maxinv;

  {
    const float qv[4] = {q4.x, q4.y, q4.z, q4.w};
#pragma unroll
    for (int j = 0; j < 4; ++j)
      if (qv[j] > th) { const int p = atomicAdd(&cnt, 1); surv[p] = t * 4 + j; }
  }
  __syncthreads();
  const int K = cnt;

  const int k4 = (t & 31) * 4;
  const int dbase = t >> 5;       // 0..7
  float4 acc4[16];
#pragma unroll
  for (int g = 0; g < 16; ++g) acc4[g] = make_float4(0.f, 0.f, 0.f, 0.f);
  float Sloc = 0.f;               // valid for t < 128 (d = t)

  for (int c0 = 0; c0 < K; c0 += 16) {
    const int C = min(16, K - c0);
    __syncthreads();
    if (t < DD) {
      const float sd = sdv[t];
      const uint32_t dg = ((uint32_t)(n * DD + t)) << 10;
      for (int s = 0; s < C; ++s) {
        const int m = surv[c0 + s];
        const float arg = (qkrow[m] - qkmax) * sd;
        const float e = __expf(arg);
        Sloc += e;
        float p = 0.f;
        if (arg > -30.f) {
          if (keep_mask(dg + (uint32_t)m)) p = e;
        }
        Pl[s][t] = p;
      }
    } else {
      const int u = t - 128;
      for (int slot = u; slot < C * 32; slot += 128) {
        const int s = slot >> 5, c = (slot & 31) * 4;
        *(float4*)&Vs[s][c] = *(const float4*)&v[(size_t)surv[c0 + s] * DD + c];
      }
    }
    __syncthreads();
    for (int s = 0; s < C; ++s) {
      const float4 vv = *(const float4*)&Vs[s][k4];
#pragma unroll
      for (int g = 0; g < 16; ++g) {
        const float p = Pl[s][g * 8 + dbase];
        acc4[g].x = fmaf(p, vv.x, acc4[g].x);
        acc4[g].y = fmaf(p, vv.y, acc4[g].y);
        acc4[g].z = fmaf(p, vv.z, acc4[g].z);
        acc4[g].w = fmaf(p, vv.w, acc4[g].w);
      }
    }
  }

  __syncthreads();
  if (t < DD) rsl[t] = 1.0f / (Sloc * 0.6f);
  __syncthreads();
  float* op = &out[(size_t)n * (DD * DD) + t * 4];
#pragma unroll
  for (int g = 0; g < 16; ++g) {
    const float rs = rsl[g * 8 + dbase];
    float4 r = acc4[g];
    r.x *= rs; r.y *= rs; r.z *= rs; r.w *= rs;
    *(float4*)&op[g * 1024] = r;
  }
}

// ---- launch --------------------------------------------------------------
extern "C" void kernel_launch(void* const* d_in, const int* in_sizes, int n_in,
                              void* d_out, int out_size, void* d_ws, size_t ws_size,
                              hipStream_t stream) {
  const float* x1 = (const float*)d_in[0];
  const float* x2 = (const float*)d_in[1];
  const float* x3 = (const float*)d_in[2];
  const float* x4 = (const float*)d_in[3];
  const float* W  = (const float*)d_in[4];
  const float* b  = (const float*)d_in[5];
  float* out = (float*)d_out;

  float* ws   = (float*)d_ws;
  float* q    = ws;                 // 1024*128
  float* k    = ws + 131072;
  float* v    = ws + 262144;
  float* sc   = ws + 393216;
  float* inv  = ws + 524288;
  float* qkm  = ws + 655360;        // 1024*1024
  float* WTp  = ws + 1703936;       // 512*128 transposed W

  wtrans_kernel<<<dim3(64), 256, 0, stream>>>(W, WTp);
  lin_kernel<<<dim3(128, 4), 256, 0, stream>>>(x1, x2, x3, x4, WTp, b, q, k, v, sc);
  mid_kernel<<<dim3(384), 256, 0, stream>>>(q, k, sc, qkm, inv);
  attn_kernel<<<NN, 256, 0, stream>>>(qkm, inv, v, out);
}

// Round 8
// 117.323 us; speedup vs baseline: 1.7825x; 1.0263x over previous
//
#include <hip/hip_runtime.h>
#include <stdint.h>
#include <math.h>

static constexpr int NN  = 1024;   // N
static constexpr int DIN = 512;    // D_IN
static constexpr int DD  = 128;    // D_OUT

// ---- threefry2x32, key = jax.random.key(42) => (0,42), partitionable ----
__device__ __forceinline__ uint32_t rotl32(uint32_t x, uint32_t r) {
  return (x << r) | (x >> (32u - r));
}

__device__ __forceinline__ bool keep_mask(uint32_t idx) {
  uint32_t x0 = 0u, x1 = idx;
  const uint32_t k0 = 0u, k1 = 42u;
  const uint32_t k2 = k0 ^ k1 ^ 0x1BD11BDAu;
  x0 += k0; x1 += k1;
#define TF_ROUND(r) { x0 += x1; x1 = rotl32(x1, r); x1 ^= x0; }
  TF_ROUND(13u) TF_ROUND(15u) TF_ROUND(26u) TF_ROUND(6u)
  x0 += k1; x1 += k2 + 1u;
  TF_ROUND(17u) TF_ROUND(29u) TF_ROUND(16u) TF_ROUND(24u)
  x0 += k2; x1 += k0 + 2u;
  TF_ROUND(13u) TF_ROUND(15u) TF_ROUND(26u) TF_ROUND(6u)
  x0 += k0; x1 += k1 + 3u;
  TF_ROUND(17u) TF_ROUND(29u) TF_ROUND(16u) TF_ROUND(24u)
  x0 += k1; x1 += k2 + 4u;
  TF_ROUND(13u) TF_ROUND(15u) TF_ROUND(26u) TF_ROUND(6u)
  x0 += k2; x1 += k0 + 5u;
#undef TF_ROUND
  const uint32_t bits = x0 ^ x1;
  const float u = __uint_as_float((bits >> 9) | 0x3f800000u) - 1.0f;
  return u < 0.6f;
}

// ---- K0: WTp[k4][d][kk] = W[d][k4*4+kk]  (grid 64, block 256) ------------
// One-time 256 KB transpose so lin can read W coalesced with d-per-lane.
__global__ __launch_bounds__(256) void wtrans_kernel(
    const float* __restrict__ W, float* __restrict__ WTp) {
  const int t = threadIdx.x;
  const int d = blockIdx.x * 2 + (t >> 7);
  const int k4 = t & 127;
  const float4 w = *(const float4*)&W[d * DIN + k4 * 4];
  *(float4*)&WTp[(size_t)k4 * (DD * 4) + d * 4] = w;
}

// ---- K1: q,k,v,scale = x_i @ W.T + b  (grid (128,4), block 256) ----------
// Restored R0 design (verified 117.5us). Session post-mortems R3/R4-6/R7:
// every rebalance of the {X-broadcast LDS, W-VMEM} split priced out at
// >= this cost. X_broadcasts/blk/k4 ~ rows_per_wave (here 16, 2x dup);
// W_traffic ~ d_per_wave (here 512KB/blk, 2x dup). R3 (X on vmcnt):
// serialized W prefetch, +18us. R7 (rows2/d128): LDS halves but W doubles,
// wash. W-in-LDS: same instr count moved onto the LDS pipe, no gain.
__global__ __launch_bounds__(256) void lin_kernel(
    const float* __restrict__ x1, const float* __restrict__ x2,
    const float* __restrict__ x3, const float* __restrict__ x4,
    const float* __restrict__ WTp, const float* __restrict__ bias,
    float* __restrict__ q, float* __restrict__ kk,
    float* __restrict__ v, float* __restrict__ sc) {
  __shared__ float Xs[8 * 516];    // 16.5 KB, stride 516 (bank-safe writes)
  const int t = threadIdx.x;
  const int n0 = blockIdx.x * 8;
  const int mat = blockIdx.y;
  const float* x = (mat == 0) ? x1 : (mat == 1) ? x2 : (mat == 2) ? x3 : x4;
  float* o = (mat == 0) ? q : (mat == 1) ? kk : (mat == 2) ? v : sc;

  // stage X: 8 rows x 512 (4 float4 per thread, coalesced)
#pragma unroll
  for (int it = 0; it < 4; ++it) {
    const int i = t + 256 * it;
    const int r = i >> 7, c = (i & 127) * 4;
    *(float4*)&Xs[r * 516 + c] = *(const float4*)&x[(size_t)(n0 + r) * DIN + c];
  }
  __syncthreads();

  const int d = t & 127;           // lane-contiguous d within each wave
  const int g2 = t >> 7;           // 0/1: which 4 n-rows (wave-uniform)
  float acc[4] = {0.f, 0.f, 0.f, 0.f};
  const float* wp = &WTp[d * 4];

#pragma unroll 4
  for (int k4 = 0; k4 < 128; ++k4) {
    const float4 w4 = *(const float4*)&wp[(size_t)k4 * (DD * 4)];
#pragma unroll
    for (int j = 0; j < 4; ++j) {
      const float4 xa = *(const float4*)&Xs[(g2 * 4 + j) * 516 + k4 * 4];
      acc[j] = fmaf(xa.x, w4.x, fmaf(xa.y, w4.y,
               fmaf(xa.z, w4.z, fmaf(xa.w, w4.w, acc[j]))));
    }
  }

  const float bd = bias[d];
#pragma unroll
  for (int j = 0; j < 4; ++j)
    o[(size_t)(n0 + g2 * 4 + j) * DD + d] = acc[j] + bd;
}

// ---- K2: fused qk = q@k.T (blocks 0..255) + colsoftmax (blocks 256..383) -
__global__ __launch_bounds__(256) void mid_kernel(
    const float* __restrict__ q, const float* __restrict__ kref,
    const float* __restrict__ sc, float* __restrict__ qkout,
    float* __restrict__ inv) {
  const int t = threadIdx.x;
  if (blockIdx.x < 256) {
    // ---- qk: 64x64 tile, 4x4 per thread ----
    __shared__ float qs[64 * 132];
    __shared__ float ks[64 * 132];
    const int tx = t & 15, ty = t >> 4;
    const int tm = (blockIdx.x & 15) * 64, tn = (blockIdx.x >> 4) * 64;
    for (int it = 0; it < 8; ++it) {
      const int i = t + 256 * it;
      const int r = i >> 5, c = (i & 31) * 4;
      *(float4*)&qs[r * 132 + c] = *(const float4*)&q[(tn + r) * DD + c];
      *(float4*)&ks[r * 132 + c] = *(const float4*)&kref[(tm + r) * DD + c];
    }
    __syncthreads();
    float acc[4][4] = {};
    for (int k0 = 0; k0 < DD; k0 += 4) {
      float4 qv[4], kv[4];
#pragma unroll
      for (int i = 0; i < 4; ++i) qv[i] = *(const float4*)&qs[(ty * 4 + i) * 132 + k0];
#pragma unroll
      for (int j = 0; j < 4; ++j) kv[j] = *(const float4*)&ks[(tx + 16 * j) * 132 + k0];
#pragma unroll
      for (int i = 0; i < 4; ++i)
#pragma unroll
        for (int j = 0; j < 4; ++j)
          acc[i][j] = fmaf(qv[i].x, kv[j].x,
                      fmaf(qv[i].y, kv[j].y,
                      fmaf(qv[i].z, kv[j].z,
                      fmaf(qv[i].w, kv[j].w, acc[i][j]))));
    }
#pragma unroll
    for (int i = 0; i < 4; ++i)
#pragma unroll
      for (int j = 0; j < 4; ++j)
        qkout[(size_t)(tn + ty * 4 + i) * NN + tm + tx + 16 * j] = acc[i][j];
  } else {
    // ---- column softmax over n for d = blockIdx.x - 256 ----
    __shared__ float red[256];
    const int d = blockIdx.x - 256;
    float vals[4];
    float mx = -INFINITY;
#pragma unroll
    for (int i = 0; i < 4; ++i) {
      vals[i] = sc[(size_t)(t + 256 * i) * DD + d];
      mx = fmaxf(mx, vals[i]);
    }
    red[t] = mx; __syncthreads();
    for (int s = 128; s > 0; s >>= 1) {
      if (t < s) red[t] = fmaxf(red[t], red[t + s]);
      __syncthreads();
    }
    mx = red[0]; __syncthreads();
    float e[4]; float sm = 0.f;
#pragma unroll
    for (int i = 0; i < 4; ++i) { e[i] = expf(vals[i] - mx); sm += e[i]; }
    red[t] = sm; __syncthreads();
    for (int s = 128; s > 0; s >>= 1) {
      if (t < s) red[t] += red[t + s];
      __syncthreads();
    }
    sm = red[0];
#pragma unroll
    for (int i = 0; i < 4; ++i)
      inv[(size_t)(t + 256 * i) * DD + d] = e[i] / sm;
  }
}

// ---- K3: sparse softmax-dropout-PV  (grid 1024, block 256) ---------------
// Survivor gate: qv > qkmax - 30*max_d(inv) => ~1-3 survivors of 1024.
// Store layout: out[n*16384 + g*1024 + t*4] -> 1 KB contiguous per
// wave-store (no partial cachelines).
__global__ __launch_bounds__(256) void attn_kernel(
    const float* __restrict__ qk, const float* __restrict__ inv_scale,
    const float* __restrict__ v, float* __restrict__ out) {
  __shared__ float qkrow[NN];      // 4 KB
  __shared__ float red[8];
  __shared__ int   surv[NN];       // 4 KB (worst case dense -> still correct)
  __shared__ float Pl[16][130];    // P chunk [s][d]
  __shared__ float Vs[16][132];    // V chunk [s][k]
  __shared__ float sdv[DD];
  __shared__ float rsl[DD];
  __shared__ int   cnt;

  const int n = blockIdx.x;
  const int t = threadIdx.x;

  const float4 q4 = *(const float4*)&qk[(size_t)n * NN + t * 4];
  *(float4*)&qkrow[t * 4] = q4;
  float mx = fmaxf(fmaxf(q4.x, q4.y), fmaxf(q4.z, q4.w));
#pragma unroll
  for (int o = 32; o > 0; o >>= 1) mx = fmaxf(mx, __shfl_xor(mx, o));
  if ((t & 63) == 0) red[t >> 6] = mx;
  float iv = 0.f;
  if (t < DD) { iv = inv_scale[n * DD + t]; sdv[t] = 1.0f / iv; }
  float miv = iv;
#pragma unroll
  for (int o = 32; o > 0; o >>= 1) miv = fmaxf(miv, __shfl_xor(miv, o));
  if ((t & 63) == 0) red[4 + (t >> 6)] = miv;
  if (t == 0) cnt = 0;
  __syncthreads();
  const float qkmax = fmaxf(fmaxf(red[0], red[1]), fmaxf(red[2], red[3]));
  const float maxinv = fmaxf(red[4], red[5]);
  const float th = qkmax - 30.f * maxinv;

  {
    const float qv[4] = {q4.x, q4.y, q4.z, q4.w};
#pragma unroll
    for (int j = 0; j < 4; ++j)
      if (qv[j] > th) { const int p = atomicAdd(&cnt, 1); surv[p] = t * 4 + j; }
  }
  __syncthreads();
  const int K = cnt;

  const int k4 = (t & 31) * 4;
  const int dbase = t >> 5;       // 0..7
  float4 acc4[16];
#pragma unroll
  for (int g = 0; g < 16; ++g) acc4[g] = make_float4(0.f, 0.f, 0.f, 0.f);
  float Sloc = 0.f;               // valid for t < 128 (d = t)

  for (int c0 = 0; c0 < K; c0 += 16) {
    const int C = min(16, K - c0);
    __syncthreads();
    if (t < DD) {
      const float sd = sdv[t];
      const uint32_t dg = ((uint32_t)(n * DD + t)) << 10;
      for (int s = 0; s < C; ++s) {
        const int m = surv[c0 + s];
        const float arg = (qkrow[m] - qkmax) * sd;
        const float e = __expf(arg);
        Sloc += e;
        float p = 0.f;
        if (arg > -30.f) {
          if (keep_mask(dg + (uint32_t)m)) p = e;
        }
        Pl[s][t] = p;
      }
    } else {
      const int u = t - 128;
      for (int slot = u; slot < C * 32; slot += 128) {
        const int s = slot >> 5, c = (slot & 31) * 4;
        *(float4*)&Vs[s][c] = *(const float4*)&v[(size_t)surv[c0 + s] * DD + c];
      }
    }
    __syncthreads();
    for (int s = 0; s < C; ++s) {
      const float4 vv = *(const float4*)&Vs[s][k4];
#pragma unroll
      for (int g = 0; g < 16; ++g) {
        const float p = Pl[s][g * 8 + dbase];
        acc4[g].x = fmaf(p, vv.x, acc4[g].x);
        acc4[g].y = fmaf(p, vv.y, acc4[g].y);
        acc4[g].z = fmaf(p, vv.z, acc4[g].z);
        acc4[g].w = fmaf(p, vv.w, acc4[g].w);
      }
    }
  }

  __syncthreads();
  if (t < DD) rsl[t] = 1.0f / (Sloc * 0.6f);
  __syncthreads();
  float* op = &out[(size_t)n * (DD * DD) + t * 4];
#pragma unroll
  for (int g = 0; g < 16; ++g) {
    const float rs = rsl[g * 8 + dbase];
    float4 r = acc4[g];
    r.x *= rs; r.y *= rs; r.z *= rs; r.w *= rs;
    *(float4*)&op[g * 1024] = r;
  }
}

// ---- launch --------------------------------------------------------------
extern "C" void kernel_launch(void* const* d_in, const int* in_sizes, int n_in,
                              void* d_out, int out_size, void* d_ws, size_t ws_size,
                              hipStream_t stream) {
  const float* x1 = (const float*)d_in[0];
  const float* x2 = (const float*)d_in[1];
  const float* x3 = (const float*)d_in[2];
  const float* x4 = (const float*)d_in[3];
  const float* W  = (const float*)d_in[4];
  const float* b  = (const float*)d_in[5];
  float* out = (float*)d_out;

  float* ws   = (float*)d_ws;
  float* q    = ws;                 // 1024*128
  float* k    = ws + 131072;
  float* v    = ws + 262144;
  float* sc   = ws + 393216;
  float* inv  = ws + 524288;
  float* qkm  = ws + 655360;        // 1024*1024
  float* WTp  = ws + 1703936;       // 512*128 transposed W

  wtrans_kernel<<<dim3(64), 256, 0, stream>>>(W, WTp);
  lin_kernel<<<dim3(128, 4), 256, 0, stream>>>(x1, x2, x3, x4, WTp, b, q, k, v, sc);
  mid_kernel<<<dim3(384), 256, 0, stream>>>(q, k, sc, qkm, inv);
  attn_kernel<<<NN, 256, 0, stream>>>(qkm, inv, v, out);
}